// Round 7
// baseline (318.795 us; speedup 1.0000x reference)
//
#include <hip/hip_runtime.h>

#define HH  1024
#define WW  1024
#define HID 256

typedef __attribute__((ext_vector_type(4))) float f32x4;
typedef __attribute__((ext_vector_type(8))) short short8;

static __device__ __forceinline__ unsigned short f2bf(float x) {
    unsigned u = __builtin_bit_cast(unsigned, x);
    u = (u + 0x7fffu + ((u >> 16) & 1u)) >> 16;   // RNE
    return (unsigned short)u;
}

// ---------------- stage 1: per-axis branch MLPs ----------------

__global__ __launch_bounds__(256) void transpose_k(
    const float* __restrict__ pw1, const float* __restrict__ pw2,
    float* __restrict__ pw1t, float* __restrict__ pw2t)
{
    __shared__ float tile[32][33];
    const float* src = blockIdx.z ? pw2 : pw1;
    float*       dst = blockIdx.z ? pw2t : pw1t;
    const int bx = blockIdx.x * 32, by = blockIdx.y * 32;
    const int tx = threadIdx.x & 31, ty0 = threadIdx.x >> 5;   // 32x8
    #pragma unroll
    for (int r = 0; r < 32; r += 8)
        tile[ty0 + r][tx] = src[(by + ty0 + r) * HID + bx + tx];
    __syncthreads();
    #pragma unroll
    for (int r = 0; r < 32; r += 8)
        dst[(bx + ty0 + r) * HID + by + tx] = tile[tx][ty0 + r];
}

__global__ __launch_bounds__(256) void branch_k(
    const float* __restrict__ x, const float* __restrict__ y,
    const float* __restrict__ bw0, const float* __restrict__ bb0,
    const float* __restrict__ bw1, const float* __restrict__ bb1,
    float* __restrict__ s0)
{
    const int t  = threadIdx.x;
    const int g0 = blockIdx.x * 8;          // 8 rows/block, axis-uniform
    const int axis = g0 >> 10;
    const float* coord = axis ? y : x;
    const float* bw = axis ? bw1 : bw0;
    const float* bb = axis ? bb1 : bb0;
    const int base = g0 & 1023;
    const float wv = bw[t], bv = bb[t];
    #pragma unroll
    for (int q = 0; q < 8; ++q)
        s0[(g0 + q) * HID + t] = __sinf(coord[base + q] * wv + bv);
}

// sout = sin(sin_in @ Wt + b). Final layer: x-rows -> fxT in MFMA-FRAGMENT
// ORDER (tile ti = i>>4; frag f covers k-range (f>>2)*128+(f&3)*32+lg*8;
// lane = lg*16+il), y-rows -> fy_f (f32 row-major).
__global__ __launch_bounds__(256) void layer_k(
    const float* __restrict__ sin_in,
    const float* __restrict__ wt,       // transposed weights [c][o]
    const float* __restrict__ bias,
    float* __restrict__ sout,
    unsigned short* __restrict__ fxT, float* __restrict__ fy_f,
    const int is_final)
{
    const int t  = threadIdx.x;
    const int g0 = blockIdx.x * 8;
    float acc[8];
    const float bv = bias[t];
    #pragma unroll
    for (int q = 0; q < 8; ++q) acc[q] = bv;
    const float* srow = sin_in + g0 * HID;  // wave-uniform -> scalar loads
    for (int c = 0; c < HID; ++c) {
        const float wv = wt[c * HID + t];   // coalesced
        #pragma unroll
        for (int q = 0; q < 8; ++q) acc[q] += srow[q * HID + c] * wv;
    }
    if (!is_final) {
        #pragma unroll
        for (int q = 0; q < 8; ++q) sout[(g0 + q) * HID + t] = __sinf(acc[q]);
    } else {
        const int f  = ((t >> 7) << 2) | ((t >> 5) & 3);   // fragment of hidden t
        const int lg = (t >> 3) & 3, e = t & 7;
        #pragma unroll
        for (int q = 0; q < 8; ++q) {
            const float h = __sinf(acc[q]);
            const int g = g0 + q;
            if (g < HH) {
                const int ti = g >> 4, il = g & 15;
                fxT[ti * 4096 + f * 512 + (lg * 16 + il) * 8 + e] = f2bf(h);
            } else {
                fy_f[(g - HH) * HID + t] = h;
            }
        }
    }
}

// ---------------- stage 2: fused outer-product + MLP head ----------------
// Block (j, half): hidden slice n in [half*128, half*128+128); wave w owns 32 n.
// A' = qw1 (.) fy[j] slice in regs. B-fragments load DIRECTLY to VGPRs from
// fragment-ordered fxT (coalesced 1KB/instr, L1/L2-resident) -> no LDS
// staging, no per-iteration barriers; waves free-run within a 16-iter segment.
__global__ __launch_bounds__(256) void fused_k(
    const float* __restrict__ qw1, const float* __restrict__ qb1,
    const float* __restrict__ qw2,
    const unsigned short* __restrict__ fxT, const float* __restrict__ fy_f,
    float* __restrict__ pout)
{
    const int j    = blockIdx.x >> 1;
    const int half = blockIdx.x & 1;
    const int tid  = threadIdx.x;
    const int l    = tid & 63;
    const int w    = tid >> 6;        // wave 0..3
    const int n0   = half * 128 + w * 32;
    const int il   = l & 15;
    const int lg   = l >> 4;          // 0..3

    // per-thread slices of qb1 / qw2 for the C/D rows this lane owns
    float qb1r[2][4], qw2r[3][2][4];
    #pragma unroll
    for (int nt = 0; nt < 2; ++nt) {
        #pragma unroll
        for (int r = 0; r < 4; ++r) {
            const int n = n0 + nt * 16 + lg * 4 + r;
            qb1r[nt][r]    = qb1[n];
            qw2r[0][nt][r] = qw2[0 * HID + n];
            qw2r[1][nt][r] = qw2[1 * HID + n];
            qw2r[2][nt][r] = qw2[2 * HID + n];
        }
    }

    // Build A' fragments: lane l holds A'[n0+nt*16+(l&15)][kt*32+lg*8 + 0..7]
    short8 afrag[2][8];
    #pragma unroll
    for (int kt = 0; kt < 8; ++kt) {
        const int kb = kt * 32 + lg * 8;
        const f32x4 fA = *(const f32x4*)&fy_f[j * HID + kb];
        const f32x4 fB = *(const f32x4*)&fy_f[j * HID + kb + 4];
        #pragma unroll
        for (int nt = 0; nt < 2; ++nt) {
            const int n = n0 + nt * 16 + il;
            const f32x4 qA = *(const f32x4*)&qw1[n * HID + kb];
            const f32x4 qB = *(const f32x4*)&qw1[n * HID + kb + 4];
            short8 f;
            f[0] = (short)f2bf(qA[0] * fA[0]);
            f[1] = (short)f2bf(qA[1] * fA[1]);
            f[2] = (short)f2bf(qA[2] * fA[2]);
            f[3] = (short)f2bf(qA[3] * fA[3]);
            f[4] = (short)f2bf(qB[0] * fB[0]);
            f[5] = (short)f2bf(qB[1] * fB[1]);
            f[6] = (short)f2bf(qB[2] * fB[2]);
            f[7] = (short)f2bf(qB[3] * fB[3]);
            afrag[nt][kt] = f;
        }
    }

    __shared__ float red[4][3][256];   // per-wave partial strips (12 KB)

    const unsigned short* fxl = fxT + l * 8;   // lane base

    for (int seg = 0; seg < 4; ++seg) {
        #pragma unroll 2
        for (int it16 = 0; it16 < 16; ++it16) {
            const int itg = seg * 16 + it16;
            const unsigned short* tb = fxl + itg * 4096;
            short8 bfrag[8];
            #pragma unroll
            for (int f = 0; f < 8; ++f)
                bfrag[f] = *(const short8*)(tb + f * 512);
            f32x4 acc[2];
            #pragma unroll
            for (int nt = 0; nt < 2; ++nt) {
                acc[nt][0] = qb1r[nt][0]; acc[nt][1] = qb1r[nt][1];
                acc[nt][2] = qb1r[nt][2]; acc[nt][3] = qb1r[nt][3];
            }
            #pragma unroll
            for (int f = 0; f < 8; ++f) {
                #pragma unroll
                for (int nt = 0; nt < 2; ++nt)
                    acc[nt] = __builtin_amdgcn_mfma_f32_16x16x32_bf16(
                        afrag[nt][f], bfrag[f], acc[nt], 0, 0, 0);
            }
            // epilogue: sin -> 3-channel dot -> intra-wave reduce -> LDS strip
            float p0 = 0.f, p1 = 0.f, p2 = 0.f;
            #pragma unroll
            for (int nt = 0; nt < 2; ++nt) {
                #pragma unroll
                for (int r = 0; r < 4; ++r) {
                    const float s = __sinf(acc[nt][r]);
                    p0 += qw2r[0][nt][r] * s;
                    p1 += qw2r[1][nt][r] * s;
                    p2 += qw2r[2][nt][r] * s;
                }
            }
            p0 += __shfl_xor(p0, 16); p0 += __shfl_xor(p0, 32);
            p1 += __shfl_xor(p1, 16); p1 += __shfl_xor(p1, 32);
            p2 += __shfl_xor(p2, 16); p2 += __shfl_xor(p2, 32);
            if (l < 16) {
                const int ic = it16 * 16 + l;
                red[w][0][ic] = p0;
                red[w][1][ic] = p1;
                red[w][2][ic] = p2;
            }
        }
        __syncthreads();   // red strips complete
        // flush partial sums (pre-bias, pre-sigmoid) to workspace
        {
            const int ib = j * HH + seg * 256 + tid;
            #pragma unroll
            for (int q = 0; q < 3; ++q) {
                const float v = red[0][q][tid] + red[1][q][tid]
                              + red[2][q][tid] + red[3][q][tid];
                pout[(half * 3 + q) * (WW * HH) + ib] = v;
            }
        }
        __syncthreads();   // red consumed before next segment overwrites
    }
}

// out = sigmoid(p_half0 + p_half1 + qb2[c]), vectorized f32x4
__global__ __launch_bounds__(256) void combine_k(
    const float* __restrict__ part, const float* __restrict__ qb2,
    float* __restrict__ out)
{
    const int t = blockIdx.x * 256 + threadIdx.x;   // f32x4 index, < 786432
    const int c = t >> 18;                          // plane = 2^20 floats = 2^18 x4
    const f32x4 a = ((const f32x4*)part)[t];
    const f32x4 b = ((const f32x4*)(part + 3 * WW * HH))[t];
    const float bias = qb2[c];
    f32x4 o;
    #pragma unroll
    for (int q = 0; q < 4; ++q)
        o[q] = 1.0f / (1.0f + __expf(-(a[q] + b[q] + bias)));
    ((f32x4*)out)[t] = o;
}

extern "C" void kernel_launch(void* const* d_in, const int* in_sizes, int n_in,
                              void* d_out, int out_size, void* d_ws, size_t ws_size,
                              hipStream_t stream)
{
    const float* x   = (const float*)d_in[0];
    const float* y   = (const float*)d_in[1];
    const float* bw0 = (const float*)d_in[2];
    const float* bb0 = (const float*)d_in[3];
    const float* bw1 = (const float*)d_in[4];
    const float* bb1 = (const float*)d_in[5];
    const float* pw1 = (const float*)d_in[6];
    const float* pb1 = (const float*)d_in[7];
    const float* pw2 = (const float*)d_in[8];
    const float* pb2 = (const float*)d_in[9];
    const float* qw1 = (const float*)d_in[10];
    const float* qb1 = (const float*)d_in[11];
    const float* qw2 = (const float*)d_in[12];
    const float* qb2 = (const float*)d_in[13];

    char* ws = (char*)d_ws;
    unsigned short* fxT = (unsigned short*)(ws);                  // 512 KB (frag order)
    float* fy_f = (float*)(ws + (512 << 10));                     // 1 MB
    float* pw1t = (float*)(ws + (1536 << 10));                    // 256 KB
    float* pw2t = (float*)(ws + (1792 << 10));                    // 256 KB
    float* s0   = (float*)(ws + (2048 << 10));                    // 2 MB
    float* s1   = (float*)(ws + (4096 << 10));                    // 2 MB
    float* part = (float*)(ws + (8192 << 10));                    // 24 MB (2x3x1M f32)
    float* out  = (float*)d_out;

    transpose_k<<<dim3(8, 8, 2), 256, 0, stream>>>(pw1, pw2, pw1t, pw2t);
    branch_k<<<256, 256, 0, stream>>>(x, y, bw0, bb0, bw1, bb1, s0);
    layer_k<<<256, 256, 0, stream>>>(s0, pw1t, pb1, s1, nullptr, nullptr, 0);
    layer_k<<<256, 256, 0, stream>>>(s1, pw2t, pb2, nullptr, fxT, fy_f, 1);
    fused_k<<<2 * WW, 256, 0, stream>>>(qw1, qb1, qw2, fxT, fy_f, part);
    combine_k<<<(3 * WW * HH / 4) / 256, 256, 0, stream>>>(part, qb2, out);
}

// Round 8
// 287.586 us; speedup vs baseline: 1.1085x; 1.1085x over previous
//
#include <hip/hip_runtime.h>

#define HH  1024
#define WW  1024
#define HID 256

typedef __attribute__((ext_vector_type(4))) float f32x4;
typedef __attribute__((ext_vector_type(8))) short short8;

static __device__ __forceinline__ unsigned short f2bf(float x) {
    unsigned u = __builtin_bit_cast(unsigned, x);
    u = (u + 0x7fffu + ((u >> 16) & 1u)) >> 16;   // RNE
    return (unsigned short)u;
}

// ---------------- stage 1: per-axis branch MLPs ----------------

__global__ __launch_bounds__(256) void transpose_k(
    const float* __restrict__ pw1, const float* __restrict__ pw2,
    float* __restrict__ pw1t, float* __restrict__ pw2t)
{
    __shared__ float tile[32][33];
    const float* src = blockIdx.z ? pw2 : pw1;
    float*       dst = blockIdx.z ? pw2t : pw1t;
    const int bx = blockIdx.x * 32, by = blockIdx.y * 32;
    const int tx = threadIdx.x & 31, ty0 = threadIdx.x >> 5;   // 32x8
    #pragma unroll
    for (int r = 0; r < 32; r += 8)
        tile[ty0 + r][tx] = src[(by + ty0 + r) * HID + bx + tx];
    __syncthreads();
    #pragma unroll
    for (int r = 0; r < 32; r += 8)
        dst[(bx + ty0 + r) * HID + by + tx] = tile[tx][ty0 + r];
}

__global__ __launch_bounds__(256) void branch_k(
    const float* __restrict__ x, const float* __restrict__ y,
    const float* __restrict__ bw0, const float* __restrict__ bb0,
    const float* __restrict__ bw1, const float* __restrict__ bb1,
    float* __restrict__ s0)
{
    const int t  = threadIdx.x;
    const int g0 = blockIdx.x * 8;          // 8 rows/block, axis-uniform
    const int axis = g0 >> 10;
    const float* coord = axis ? y : x;
    const float* bw = axis ? bw1 : bw0;
    const float* bb = axis ? bb1 : bb0;
    const int base = g0 & 1023;
    const float wv = bw[t], bv = bb[t];
    #pragma unroll
    for (int q = 0; q < 8; ++q)
        s0[(g0 + q) * HID + t] = __sinf(coord[base + q] * wv + bv);
}

// sout = sin(sin_in @ Wt + b). Final layer: x-rows -> fxT in MFMA-FRAGMENT
// ORDER (tile ti = i>>4; frag f covers k-range (f>>2)*128+(f&3)*32+lg*8;
// lane = lg*16+il), y-rows -> fy_f (f32 row-major).
__global__ __launch_bounds__(256) void layer_k(
    const float* __restrict__ sin_in,
    const float* __restrict__ wt,       // transposed weights [c][o]
    const float* __restrict__ bias,
    float* __restrict__ sout,
    unsigned short* __restrict__ fxT, float* __restrict__ fy_f,
    const int is_final)
{
    const int t  = threadIdx.x;
    const int g0 = blockIdx.x * 8;
    float acc[8];
    const float bv = bias[t];
    #pragma unroll
    for (int q = 0; q < 8; ++q) acc[q] = bv;
    const float* srow = sin_in + g0 * HID;  // wave-uniform -> scalar loads
    for (int c = 0; c < HID; ++c) {
        const float wv = wt[c * HID + t];   // coalesced
        #pragma unroll
        for (int q = 0; q < 8; ++q) acc[q] += srow[q * HID + c] * wv;
    }
    if (!is_final) {
        #pragma unroll
        for (int q = 0; q < 8; ++q) sout[(g0 + q) * HID + t] = __sinf(acc[q]);
    } else {
        const int f  = ((t >> 7) << 2) | ((t >> 5) & 3);   // fragment of hidden t
        const int lg = (t >> 3) & 3, e = t & 7;
        #pragma unroll
        for (int q = 0; q < 8; ++q) {
            const float h = __sinf(acc[q]);
            const int g = g0 + q;
            if (g < HH) {
                const int ti = g >> 4, il = g & 15;
                fxT[ti * 4096 + f * 512 + (lg * 16 + il) * 8 + e] = f2bf(h);
            } else {
                fy_f[(g - HH) * HID + t] = h;
            }
        }
    }
}

// ---------------- stage 2: fused outer-product + MLP head ----------------
// One block per j (full HID). 4 waves; wave w owns n in [64w, 64w+64)
// -> 32 MFMA per wave-iteration per 8 KB B-tile (B-demand 52 B/cy/CU from
// LDS, under the 128 B/cy pipe; L1 only sees the 8 KB/iter linear stage).
// A' = qw1 (.) fy[j] in regs (afrag[4][8], AGPR-placeable). fxT is already
// in fragment order -> STAGE is a linear 8 KB copy via global_load_lds;
// ring of 3 slots, counted s_waitcnt vmcnt(2) + raw s_barrier (loads never
// drain to 0). ds_read_b128 at l*16 + f*1024: zero bank conflicts.
__global__ __launch_bounds__(256) void fused_k(
    const float* __restrict__ qw1, const float* __restrict__ qb1,
    const float* __restrict__ qw2, const float* __restrict__ qb2,
    const unsigned short* __restrict__ fxT, const float* __restrict__ fy_f,
    float* __restrict__ out)
{
    const int j   = blockIdx.x;
    const int tid = threadIdx.x;
    const int l   = tid & 63;
    const int w   = tid >> 6;        // wave 0..3
    const int n0  = w * 64;
    const int il  = l & 15;
    const int lg  = l >> 4;          // 0..3

    // per-thread slices of qb1 / qw2 for the C/D rows this lane owns
    float qb1r[4][4], qw2r[3][4][4];
    #pragma unroll
    for (int nt = 0; nt < 4; ++nt) {
        #pragma unroll
        for (int r = 0; r < 4; ++r) {
            const int n = n0 + nt * 16 + lg * 4 + r;
            qb1r[nt][r]    = qb1[n];
            qw2r[0][nt][r] = qw2[0 * HID + n];
            qw2r[1][nt][r] = qw2[1 * HID + n];
            qw2r[2][nt][r] = qw2[2 * HID + n];
        }
    }
    const float qb2v0 = qb2[0], qb2v1 = qb2[1], qb2v2 = qb2[2];

    // Build A' fragments: lane l holds A'[n0+nt*16+(l&15)][kt*32+lg*8 + 0..7]
    short8 afrag[4][8];
    #pragma unroll
    for (int kt = 0; kt < 8; ++kt) {
        const int kb = kt * 32 + lg * 8;
        const f32x4 fA = *(const f32x4*)&fy_f[j * HID + kb];
        const f32x4 fB = *(const f32x4*)&fy_f[j * HID + kb + 4];
        #pragma unroll
        for (int nt = 0; nt < 4; ++nt) {
            const int n = n0 + nt * 16 + il;
            const f32x4 qA = *(const f32x4*)&qw1[n * HID + kb];
            const f32x4 qB = *(const f32x4*)&qw1[n * HID + kb + 4];
            short8 f;
            f[0] = (short)f2bf(qA[0] * fA[0]);
            f[1] = (short)f2bf(qA[1] * fA[1]);
            f[2] = (short)f2bf(qA[2] * fA[2]);
            f[3] = (short)f2bf(qA[3] * fA[3]);
            f[4] = (short)f2bf(qB[0] * fB[0]);
            f[5] = (short)f2bf(qB[1] * fB[1]);
            f[6] = (short)f2bf(qB[2] * fB[2]);
            f[7] = (short)f2bf(qB[3] * fB[3]);
            afrag[nt][kt] = f;
        }
    }

    __shared__ __attribute__((aligned(16))) char tile[3][8192]; // frag-order ring
    __shared__ float red[4][3][256];                            // partial strips

    const char* fxb = (const char*)fxT;
    // linear stage: wave w copies fragments f = 2w, 2w+1 (1 KB each)
    const unsigned off0 = (unsigned)((w * 2 + 0) * 1024 + l * 16);
    const unsigned off1 = (unsigned)((w * 2 + 1) * 1024 + l * 16);

#define STAGE(slot, tidx)                                                        \
    do {                                                                         \
        const char* _src = fxb + (unsigned)(tidx) * 8192u;                       \
        __builtin_amdgcn_global_load_lds(                                        \
            (const __attribute__((address_space(1))) unsigned*)(_src + off0),    \
            (__attribute__((address_space(3))) unsigned*)(&tile[slot][off0]),    \
            16, 0, 0);                                                           \
        __builtin_amdgcn_global_load_lds(                                        \
            (const __attribute__((address_space(1))) unsigned*)(_src + off1),    \
            (__attribute__((address_space(3))) unsigned*)(&tile[slot][off1]),    \
            16, 0, 0);                                                           \
    } while (0)

#define WAITBAR asm volatile("s_waitcnt vmcnt(2)\n\ts_barrier" ::: "memory")

    // prologue: stage tiles 0,1 into slots 0,1; wait for tile 0 only
    STAGE(0, 0);
    STAGE(1, 1);
    WAITBAR;

    int itg = 0;
    int cur = 0;                       // slot of tile itg
    for (int seg = 0; seg < 4; ++seg) {
        for (int it16 = 0; it16 < 16; ++it16, ++itg) {
            // issue stage of tile itg+2 (wraps: dummy re-stage keeps counts uniform)
            {
                int s2 = cur + 2; if (s2 >= 3) s2 -= 3;
                const int tidx = (itg + 2) & 63;
                switch (s2) {          // compile-time slot addresses
                    case 0: STAGE(0, tidx); break;
                    case 1: STAGE(1, tidx); break;
                    default: STAGE(2, tidx); break;
                }
            }
            f32x4 acc[4];
            #pragma unroll
            for (int nt = 0; nt < 4; ++nt) {
                acc[nt][0] = qb1r[nt][0]; acc[nt][1] = qb1r[nt][1];
                acc[nt][2] = qb1r[nt][2]; acc[nt][3] = qb1r[nt][3];
            }
            const char* tb = &tile[cur][l * 16];
            #pragma unroll
            for (int f = 0; f < 8; ++f) {
                const short8 bfrag = *(const short8*)(tb + f * 1024);
                #pragma unroll
                for (int nt = 0; nt < 4; ++nt)
                    acc[nt] = __builtin_amdgcn_mfma_f32_16x16x32_bf16(
                        afrag[nt][f], bfrag, acc[nt], 0, 0, 0);
            }
            // epilogue: sin -> 3-channel dot -> intra-wave reduce -> LDS strip
            float p0 = 0.f, p1 = 0.f, p2 = 0.f;
            #pragma unroll
            for (int nt = 0; nt < 4; ++nt) {
                #pragma unroll
                for (int r = 0; r < 4; ++r) {
                    const float s = __sinf(acc[nt][r]);
                    p0 += qw2r[0][nt][r] * s;
                    p1 += qw2r[1][nt][r] * s;
                    p2 += qw2r[2][nt][r] * s;
                }
            }
            p0 += __shfl_xor(p0, 16); p0 += __shfl_xor(p0, 32);
            p1 += __shfl_xor(p1, 16); p1 += __shfl_xor(p1, 32);
            p2 += __shfl_xor(p2, 16); p2 += __shfl_xor(p2, 32);
            if (l < 16) {
                const int ic = it16 * 16 + l;
                red[w][0][ic] = p0;
                red[w][1][ic] = p1;
                red[w][2][ic] = p2;
            }
            WAITBAR;           // stage[itg+1] may stay in flight; stage[itg] done
            cur = cur + 1 == 3 ? 0 : cur + 1;
        }
        // flush: 768 outputs, coalesced
        {
            const int ib = j * HH + seg * 256 + tid;
            #pragma unroll
            for (int q = 0; q < 3; ++q) {
                const float v = red[0][q][tid] + red[1][q][tid]
                              + red[2][q][tid] + red[3][q][tid]
                              + (q == 0 ? qb2v0 : (q == 1 ? qb2v1 : qb2v2));
                out[q * (WW * HH) + ib] = 1.0f / (1.0f + __expf(-v));
            }
        }
        // red consumed before next segment's epilogues overwrite it
        asm volatile("s_barrier" ::: "memory");
    }
#undef STAGE
#undef WAITBAR
}

extern "C" void kernel_launch(void* const* d_in, const int* in_sizes, int n_in,
                              void* d_out, int out_size, void* d_ws, size_t ws_size,
                              hipStream_t stream)
{
    const float* x   = (const float*)d_in[0];
    const float* y   = (const float*)d_in[1];
    const float* bw0 = (const float*)d_in[2];
    const float* bb0 = (const float*)d_in[3];
    const float* bw1 = (const float*)d_in[4];
    const float* bb1 = (const float*)d_in[5];
    const float* pw1 = (const float*)d_in[6];
    const float* pb1 = (const float*)d_in[7];
    const float* pw2 = (const float*)d_in[8];
    const float* pb2 = (const float*)d_in[9];
    const float* qw1 = (const float*)d_in[10];
    const float* qb1 = (const float*)d_in[11];
    const float* qw2 = (const float*)d_in[12];
    const float* qb2 = (const float*)d_in[13];

    char* ws = (char*)d_ws;
    unsigned short* fxT = (unsigned short*)(ws);                  // 512 KB (frag order)
    float* fy_f = (float*)(ws + (512 << 10));                     // 1 MB
    float* pw1t = (float*)(ws + (1536 << 10));                    // 256 KB
    float* pw2t = (float*)(ws + (1792 << 10));                    // 256 KB
    float* s0   = (float*)(ws + (2048 << 10));                    // 2 MB
    float* s1   = (float*)(ws + (4096 << 10));                    // 2 MB
    float* out  = (float*)d_out;

    transpose_k<<<dim3(8, 8, 2), 256, 0, stream>>>(pw1, pw2, pw1t, pw2t);
    branch_k<<<256, 256, 0, stream>>>(x, y, bw0, bb0, bw1, bb1, s0);
    layer_k<<<256, 256, 0, stream>>>(s0, pw1t, pb1, s1, nullptr, nullptr, 0);
    layer_k<<<256, 256, 0, stream>>>(s1, pw2t, pb2, nullptr, fxT, fy_f, 1);
    fused_k<<<WW, 256, 0, stream>>>(qw1, qb1, qw2, qb2, fxT, fy_f, out);
}

// Round 10
// 234.210 us; speedup vs baseline: 1.3611x; 1.2279x over previous
//
#include <hip/hip_runtime.h>

#define HH  1024
#define WW  1024
#define HID 256

typedef __attribute__((ext_vector_type(4))) float f32x4;
typedef __attribute__((ext_vector_type(8))) short short8;

static __device__ __forceinline__ unsigned short f2bf(float x) {
    unsigned u = __builtin_bit_cast(unsigned, x);
    u = (u + 0x7fffu + ((u >> 16) & 1u)) >> 16;   // RNE
    return (unsigned short)u;
}

// ---------------- stage 1: per-axis branch MLPs ----------------

__global__ __launch_bounds__(256) void transpose_k(
    const float* __restrict__ pw1, const float* __restrict__ pw2,
    float* __restrict__ pw1t, float* __restrict__ pw2t)
{
    __shared__ float tile[32][33];
    const float* src = blockIdx.z ? pw2 : pw1;
    float*       dst = blockIdx.z ? pw2t : pw1t;
    const int bx = blockIdx.x * 32, by = blockIdx.y * 32;
    const int tx = threadIdx.x & 31, ty0 = threadIdx.x >> 5;   // 32x8
    #pragma unroll
    for (int r = 0; r < 32; r += 8)
        tile[ty0 + r][tx] = src[(by + ty0 + r) * HID + bx + tx];
    __syncthreads();
    #pragma unroll
    for (int r = 0; r < 32; r += 8)
        dst[(bx + ty0 + r) * HID + by + tx] = tile[tx][ty0 + r];
}

__global__ __launch_bounds__(256) void branch_k(
    const float* __restrict__ x, const float* __restrict__ y,
    const float* __restrict__ bw0, const float* __restrict__ bb0,
    const float* __restrict__ bw1, const float* __restrict__ bb1,
    float* __restrict__ s0)
{
    const int t  = threadIdx.x;
    const int g0 = blockIdx.x * 8;          // 8 rows/block, axis-uniform
    const int axis = g0 >> 10;
    const float* coord = axis ? y : x;
    const float* bw = axis ? bw1 : bw0;
    const float* bb = axis ? bb1 : bb0;
    const int base = g0 & 1023;
    const float wv = bw[t], bv = bb[t];
    #pragma unroll
    for (int q = 0; q < 8; ++q)
        s0[(g0 + q) * HID + t] = __sinf(coord[base + q] * wv + bv);
}

// sout = sin(sin_in @ Wt + b). Final layer: x-rows -> fxT in MFMA-FRAGMENT
// ORDER (tile ti = i>>4; frag f covers k-range (f>>2)*128+(f&3)*32+lg*8;
// lane = lg*16+il), y-rows -> fy_f (f32 row-major).
__global__ __launch_bounds__(256) void layer_k(
    const float* __restrict__ sin_in,
    const float* __restrict__ wt,       // transposed weights [c][o]
    const float* __restrict__ bias,
    float* __restrict__ sout,
    unsigned short* __restrict__ fxT, float* __restrict__ fy_f,
    const int is_final)
{
    const int t  = threadIdx.x;
    const int g0 = blockIdx.x * 8;
    float acc[8];
    const float bv = bias[t];
    #pragma unroll
    for (int q = 0; q < 8; ++q) acc[q] = bv;
    const float* srow = sin_in + g0 * HID;  // wave-uniform -> scalar loads
    for (int c = 0; c < HID; ++c) {
        const float wv = wt[c * HID + t];   // coalesced
        #pragma unroll
        for (int q = 0; q < 8; ++q) acc[q] += srow[q * HID + c] * wv;
    }
    if (!is_final) {
        #pragma unroll
        for (int q = 0; q < 8; ++q) sout[(g0 + q) * HID + t] = __sinf(acc[q]);
    } else {
        const int f  = ((t >> 7) << 2) | ((t >> 5) & 3);   // fragment of hidden t
        const int lg = (t >> 3) & 3, e = t & 7;
        #pragma unroll
        for (int q = 0; q < 8; ++q) {
            const float h = __sinf(acc[q]);
            const int g = g0 + q;
            if (g < HH) {
                const int ti = g >> 4, il = g & 15;
                fxT[ti * 4096 + f * 512 + (lg * 16 + il) * 8 + e] = f2bf(h);
            } else {
                fy_f[(g - HH) * HID + t] = h;
            }
        }
    }
}

// ---------------- stage 2: fused outer-product + MLP head ----------------
// One block per j (full HID). 4 waves; wave w owns n in [64w, 64w+64).
// A' = qw1 (.) fy[j] in AGPRs + working set capped to 128 VGPR by
// __launch_bounds__(256,2) -> 2 blocks/CU. fxT in fragment order -> STAGE
// is a linear 8 KB copy via global_load_lds; ring of 3 slots with counted
// s_waitcnt vmcnt(2) (loads never drain to 0).
// RACE FIX (R9): every raw s_barrier now waits lgkmcnt(0) first — ds_writes
// to `red` must drain before other waves read it past the barrier (ISA §8:
// "s_waitcnt first if data dep"). vmcnt(2) semantics unchanged, so the
// global_load_lds pipeline stays in flight.
__global__ __launch_bounds__(256, 2) void fused_k(
    const float* __restrict__ qw1, const float* __restrict__ qb1,
    const float* __restrict__ qw2, const float* __restrict__ qb2,
    const unsigned short* __restrict__ fxT, const float* __restrict__ fy_f,
    float* __restrict__ out)
{
    const int j   = blockIdx.x;
    const int tid = threadIdx.x;
    const int l   = tid & 63;
    const int w   = tid >> 6;        // wave 0..3
    const int n0  = w * 64;
    const int il  = l & 15;
    const int lg  = l >> 4;          // 0..3

    // per-thread slices of qb1 / qw2 for the C/D rows this lane owns
    float qb1r[4][4], qw2r[3][4][4];
    #pragma unroll
    for (int nt = 0; nt < 4; ++nt) {
        #pragma unroll
        for (int r = 0; r < 4; ++r) {
            const int n = n0 + nt * 16 + lg * 4 + r;
            qb1r[nt][r]    = qb1[n];
            qw2r[0][nt][r] = qw2[0 * HID + n];
            qw2r[1][nt][r] = qw2[1 * HID + n];
            qw2r[2][nt][r] = qw2[2 * HID + n];
        }
    }
    const float qb2v0 = qb2[0], qb2v1 = qb2[1], qb2v2 = qb2[2];

    // Build A' fragments: lane l holds A'[n0+nt*16+(l&15)][kt*32+lg*8 + 0..7]
    short8 afrag[4][8];
    #pragma unroll
    for (int kt = 0; kt < 8; ++kt) {
        const int kb = kt * 32 + lg * 8;
        const f32x4 fA = *(const f32x4*)&fy_f[j * HID + kb];
        const f32x4 fB = *(const f32x4*)&fy_f[j * HID + kb + 4];
        #pragma unroll
        for (int nt = 0; nt < 4; ++nt) {
            const int n = n0 + nt * 16 + il;
            const f32x4 qA = *(const f32x4*)&qw1[n * HID + kb];
            const f32x4 qB = *(const f32x4*)&qw1[n * HID + kb + 4];
            short8 f;
            f[0] = (short)f2bf(qA[0] * fA[0]);
            f[1] = (short)f2bf(qA[1] * fA[1]);
            f[2] = (short)f2bf(qA[2] * fA[2]);
            f[3] = (short)f2bf(qA[3] * fA[3]);
            f[4] = (short)f2bf(qB[0] * fB[0]);
            f[5] = (short)f2bf(qB[1] * fB[1]);
            f[6] = (short)f2bf(qB[2] * fB[2]);
            f[7] = (short)f2bf(qB[3] * fB[3]);
            afrag[nt][kt] = f;
        }
    }

    __shared__ __attribute__((aligned(16))) char tile[3][8192]; // frag-order ring
    __shared__ float red[4][3][256];                            // partial strips

    const char* fxb = (const char*)fxT;
    // linear stage: wave w copies fragments f = 2w, 2w+1 (1 KB each)
    const unsigned off0 = (unsigned)((w * 2 + 0) * 1024 + l * 16);
    const unsigned off1 = (unsigned)((w * 2 + 1) * 1024 + l * 16);

#define STAGE(slot, tidx)                                                        \
    do {                                                                         \
        const char* _src = fxb + (unsigned)(tidx) * 8192u;                       \
        __builtin_amdgcn_global_load_lds(                                        \
            (const __attribute__((address_space(1))) unsigned*)(_src + off0),    \
            (__attribute__((address_space(3))) unsigned*)(&tile[slot][off0]),    \
            16, 0, 0);                                                           \
        __builtin_amdgcn_global_load_lds(                                        \
            (const __attribute__((address_space(1))) unsigned*)(_src + off1),    \
            (__attribute__((address_space(3))) unsigned*)(&tile[slot][off1]),    \
            16, 0, 0);                                                           \
    } while (0)

// counted vmem wait (pipeline stays filled) + FULL lds drain (cross-wave
// visibility of red/ds ops) + barrier
#define WAITBAR asm volatile("s_waitcnt vmcnt(2) lgkmcnt(0)\n\ts_barrier" ::: "memory")

    // prologue: stage tiles 0,1 into slots 0,1; wait for tile 0 only
    STAGE(0, 0);
    STAGE(1, 1);
    WAITBAR;

    int itg = 0;
    int cur = 0;                       // slot of tile itg
    for (int seg = 0; seg < 4; ++seg) {
        for (int it16 = 0; it16 < 16; ++it16, ++itg) {
            // issue stage of tile itg+2 (wraps: dummy re-stage keeps counts uniform)
            {
                int s2 = cur + 2; if (s2 >= 3) s2 -= 3;
                const int tidx = (itg + 2) & 63;
                switch (s2) {          // compile-time slot addresses
                    case 0: STAGE(0, tidx); break;
                    case 1: STAGE(1, tidx); break;
                    default: STAGE(2, tidx); break;
                }
            }
            f32x4 acc[4];
            #pragma unroll
            for (int nt = 0; nt < 4; ++nt) {
                acc[nt][0] = qb1r[nt][0]; acc[nt][1] = qb1r[nt][1];
                acc[nt][2] = qb1r[nt][2]; acc[nt][3] = qb1r[nt][3];
            }
            const char* tb = &tile[cur][l * 16];
            #pragma unroll
            for (int f = 0; f < 8; ++f) {
                const short8 bfrag = *(const short8*)(tb + f * 1024);
                #pragma unroll
                for (int nt = 0; nt < 4; ++nt)
                    acc[nt] = __builtin_amdgcn_mfma_f32_16x16x32_bf16(
                        afrag[nt][f], bfrag, acc[nt], 0, 0, 0);
            }
            // epilogue: sin -> 3-channel dot -> intra-wave reduce -> LDS strip
            float p0 = 0.f, p1 = 0.f, p2 = 0.f;
            #pragma unroll
            for (int nt = 0; nt < 4; ++nt) {
                #pragma unroll
                for (int r = 0; r < 4; ++r) {
                    const float s = __sinf(acc[nt][r]);
                    p0 += qw2r[0][nt][r] * s;
                    p1 += qw2r[1][nt][r] * s;
                    p2 += qw2r[2][nt][r] * s;
                }
            }
            p0 += __shfl_xor(p0, 16); p0 += __shfl_xor(p0, 32);
            p1 += __shfl_xor(p1, 16); p1 += __shfl_xor(p1, 32);
            p2 += __shfl_xor(p2, 16); p2 += __shfl_xor(p2, 32);
            if (l < 16) {
                const int ic = it16 * 16 + l;
                red[w][0][ic] = p0;
                red[w][1][ic] = p1;
                red[w][2][ic] = p2;
            }
            WAITBAR;           // stage[itg+1] stays in flight; stage[itg] + red done
            cur = cur + 1 == 3 ? 0 : cur + 1;
        }
        // flush: 768 outputs, coalesced
        {
            const int ib = j * HH + seg * 256 + tid;
            #pragma unroll
            for (int q = 0; q < 3; ++q) {
                const float v = red[0][q][tid] + red[1][q][tid]
                              + red[2][q][tid] + red[3][q][tid]
                              + (q == 0 ? qb2v0 : (q == 1 ? qb2v1 : qb2v2));
                out[q * (WW * HH) + ib] = 1.0f / (1.0f + __expf(-v));
            }
        }
        // red consumed (flush ds_reads drained) before next segment overwrites
        asm volatile("s_waitcnt lgkmcnt(0)\n\ts_barrier" ::: "memory");
    }
#undef STAGE
#undef WAITBAR
}

extern "C" void kernel_launch(void* const* d_in, const int* in_sizes, int n_in,
                              void* d_out, int out_size, void* d_ws, size_t ws_size,
                              hipStream_t stream)
{
    const float* x   = (const float*)d_in[0];
    const float* y   = (const float*)d_in[1];
    const float* bw0 = (const float*)d_in[2];
    const float* bb0 = (const float*)d_in[3];
    const float* bw1 = (const float*)d_in[4];
    const float* bb1 = (const float*)d_in[5];
    const float* pw1 = (const float*)d_in[6];
    const float* pb1 = (const float*)d_in[7];
    const float* pw2 = (const float*)d_in[8];
    const float* pb2 = (const float*)d_in[9];
    const float* qw1 = (const float*)d_in[10];
    const float* qb1 = (const float*)d_in[11];
    const float* qw2 = (const float*)d_in[12];
    const float* qb2 = (const float*)d_in[13];

    char* ws = (char*)d_ws;
    unsigned short* fxT = (unsigned short*)(ws);                  // 512 KB (frag order)
    float* fy_f = (float*)(ws + (512 << 10));                     // 1 MB
    float* pw1t = (float*)(ws + (1536 << 10));                    // 256 KB
    float* pw2t = (float*)(ws + (1792 << 10));                    // 256 KB
    float* s0   = (float*)(ws + (2048 << 10));                    // 2 MB
    float* s1   = (float*)(ws + (4096 << 10));                    // 2 MB
    float* out  = (float*)d_out;

    transpose_k<<<dim3(8, 8, 2), 256, 0, stream>>>(pw1, pw2, pw1t, pw2t);
    branch_k<<<256, 256, 0, stream>>>(x, y, bw0, bb0, bw1, bb1, s0);
    layer_k<<<256, 256, 0, stream>>>(s0, pw1t, pb1, s1, nullptr, nullptr, 0);
    layer_k<<<256, 256, 0, stream>>>(s1, pw2t, pb2, nullptr, fxT, fy_f, 1);
    fused_k<<<WW, 256, 0, stream>>>(qw1, qb1, qw2, qb2, fxT, fy_f, out);
}

// Round 11
// 231.437 us; speedup vs baseline: 1.3775x; 1.0120x over previous
//
#include <hip/hip_runtime.h>

#define HH  1024
#define WW  1024
#define HID 256

typedef __attribute__((ext_vector_type(4))) float f32x4;
typedef __attribute__((ext_vector_type(8))) short short8;

static __device__ __forceinline__ unsigned short f2bf(float x) {
    unsigned u = __builtin_bit_cast(unsigned, x);
    u = (u + 0x7fffu + ((u >> 16) & 1u)) >> 16;   // RNE
    return (unsigned short)u;
}

// ---------------- stage 1: per-axis branch MLPs ----------------

__global__ __launch_bounds__(256) void transpose_k(
    const float* __restrict__ pw1, const float* __restrict__ pw2,
    float* __restrict__ pw1t, float* __restrict__ pw2t)
{
    __shared__ float tile[32][33];
    const float* src = blockIdx.z ? pw2 : pw1;
    float*       dst = blockIdx.z ? pw2t : pw1t;
    const int bx = blockIdx.x * 32, by = blockIdx.y * 32;
    const int tx = threadIdx.x & 31, ty0 = threadIdx.x >> 5;   // 32x8
    #pragma unroll
    for (int r = 0; r < 32; r += 8)
        tile[ty0 + r][tx] = src[(by + ty0 + r) * HID + bx + tx];
    __syncthreads();
    #pragma unroll
    for (int r = 0; r < 32; r += 8)
        dst[(bx + ty0 + r) * HID + by + tx] = tile[tx][ty0 + r];
}

__global__ __launch_bounds__(256) void branch_k(
    const float* __restrict__ x, const float* __restrict__ y,
    const float* __restrict__ bw0, const float* __restrict__ bb0,
    const float* __restrict__ bw1, const float* __restrict__ bb1,
    float* __restrict__ s0)
{
    const int t  = threadIdx.x;
    const int g0 = blockIdx.x * 8;          // 8 rows/block, axis-uniform
    const int axis = g0 >> 10;
    const float* coord = axis ? y : x;
    const float* bw = axis ? bw1 : bw0;
    const float* bb = axis ? bb1 : bb0;
    const int base = g0 & 1023;
    const float wv = bw[t], bv = bb[t];
    #pragma unroll
    for (int q = 0; q < 8; ++q)
        s0[(g0 + q) * HID + t] = __sinf(coord[base + q] * wv + bv);
}

// sout = sin(sin_in @ Wt + b). Final layer: x-rows -> fxT in MFMA-FRAGMENT
// ORDER (tile ti = i>>4; frag f covers k-range (f>>2)*128+(f&3)*32+lg*8;
// lane = lg*16+il), y-rows -> fy_f (f32 row-major).
__global__ __launch_bounds__(256) void layer_k(
    const float* __restrict__ sin_in,
    const float* __restrict__ wt,       // transposed weights [c][o]
    const float* __restrict__ bias,
    float* __restrict__ sout,
    unsigned short* __restrict__ fxT, float* __restrict__ fy_f,
    const int is_final)
{
    const int t  = threadIdx.x;
    const int g0 = blockIdx.x * 8;
    float acc[8];
    const float bv = bias[t];
    #pragma unroll
    for (int q = 0; q < 8; ++q) acc[q] = bv;
    const float* srow = sin_in + g0 * HID;  // wave-uniform -> scalar loads
    for (int c = 0; c < HID; ++c) {
        const float wv = wt[c * HID + t];   // coalesced
        #pragma unroll
        for (int q = 0; q < 8; ++q) acc[q] += srow[q * HID + c] * wv;
    }
    if (!is_final) {
        #pragma unroll
        for (int q = 0; q < 8; ++q) sout[(g0 + q) * HID + t] = __sinf(acc[q]);
    } else {
        const int f  = ((t >> 7) << 2) | ((t >> 5) & 3);   // fragment of hidden t
        const int lg = (t >> 3) & 3, e = t & 7;
        #pragma unroll
        for (int q = 0; q < 8; ++q) {
            const float h = __sinf(acc[q]);
            const int g = g0 + q;
            if (g < HH) {
                const int ti = g >> 4, il = g & 15;
                fxT[ti * 4096 + f * 512 + (lg * 16 + il) * 8 + e] = f2bf(h);
            } else {
                fy_f[(g - HH) * HID + t] = h;
            }
        }
    }
}

// ---------------- stage 2: fused outer-product + MLP head ----------------
// One block per j (full HID). 4 waves; wave w owns n in [64w, 64w+64).
// A' = qw1 (.) fy[j] in AGPRs; __launch_bounds__(256,2) -> 2 blocks/CU.
// 2-TILE SUPERSTEPS (R11): ring of 2 superslots (16 KB = 2 tiles each).
// Per superstep: compute 2 tiles with independent acc/bfrag chains (2x ILP),
// ONE barrier, refill cur slot (4 linear gl_lds from contiguous 16 KB),
// counted vmcnt(4) (prev slot drained, new loads stay in flight).
// After flush stores: vmcnt(7) (vmcnt counts the 3 stores too).
__global__ __launch_bounds__(256, 2) void fused_k(
    const float* __restrict__ qw1, const float* __restrict__ qb1,
    const float* __restrict__ qw2, const float* __restrict__ qb2,
    const unsigned short* __restrict__ fxT, const float* __restrict__ fy_f,
    float* __restrict__ out)
{
    const int j   = blockIdx.x;
    const int tid = threadIdx.x;
    const int l   = tid & 63;
    const int w   = tid >> 6;        // wave 0..3
    const int n0  = w * 64;
    const int il  = l & 15;
    const int lg  = l >> 4;          // 0..3

    // per-thread slices of qb1 / qw2 for the C/D rows this lane owns
    float qb1r[4][4], qw2r[3][4][4];
    #pragma unroll
    for (int nt = 0; nt < 4; ++nt) {
        #pragma unroll
        for (int r = 0; r < 4; ++r) {
            const int n = n0 + nt * 16 + lg * 4 + r;
            qb1r[nt][r]    = qb1[n];
            qw2r[0][nt][r] = qw2[0 * HID + n];
            qw2r[1][nt][r] = qw2[1 * HID + n];
            qw2r[2][nt][r] = qw2[2 * HID + n];
        }
    }
    const float qb2v0 = qb2[0], qb2v1 = qb2[1], qb2v2 = qb2[2];

    // Build A' fragments: lane l holds A'[n0+nt*16+(l&15)][kt*32+lg*8 + 0..7]
    short8 afrag[4][8];
    #pragma unroll
    for (int kt = 0; kt < 8; ++kt) {
        const int kb = kt * 32 + lg * 8;
        const f32x4 fA = *(const f32x4*)&fy_f[j * HID + kb];
        const f32x4 fB = *(const f32x4*)&fy_f[j * HID + kb + 4];
        #pragma unroll
        for (int nt = 0; nt < 4; ++nt) {
            const int n = n0 + nt * 16 + il;
            const f32x4 qA = *(const f32x4*)&qw1[n * HID + kb];
            const f32x4 qB = *(const f32x4*)&qw1[n * HID + kb + 4];
            short8 f;
            f[0] = (short)f2bf(qA[0] * fA[0]);
            f[1] = (short)f2bf(qA[1] * fA[1]);
            f[2] = (short)f2bf(qA[2] * fA[2]);
            f[3] = (short)f2bf(qA[3] * fA[3]);
            f[4] = (short)f2bf(qB[0] * fB[0]);
            f[5] = (short)f2bf(qB[1] * fB[1]);
            f[6] = (short)f2bf(qB[2] * fB[2]);
            f[7] = (short)f2bf(qB[3] * fB[3]);
            afrag[nt][kt] = f;
        }
    }

    __shared__ __attribute__((aligned(16))) char tile[2][16384]; // 2-tile superslots
    __shared__ float red[4][3][256];                             // partial strips

    const char* fxb = (const char*)fxT;
    // linear stage offsets: wave w copies fragments f = 2w, 2w+1 of each tile
    const unsigned off0 = (unsigned)((w * 2 + 0) * 1024 + l * 16);
    const unsigned off1 = (unsigned)((w * 2 + 1) * 1024 + l * 16);

// stage 2 consecutive tiles (16 KB contiguous at superIdx*16384) -> 4 loads
#define STAGE2(slot, sidx)                                                       \
    do {                                                                         \
        const char* _src = fxb + (unsigned)(sidx) * 16384u;                      \
        __builtin_amdgcn_global_load_lds(                                        \
            (const __attribute__((address_space(1))) unsigned*)(_src + off0),    \
            (__attribute__((address_space(3))) unsigned*)(&tile[slot][off0]),    \
            16, 0, 0);                                                           \
        __builtin_amdgcn_global_load_lds(                                        \
            (const __attribute__((address_space(1))) unsigned*)(_src + off1),    \
            (__attribute__((address_space(3))) unsigned*)(&tile[slot][off1]),    \
            16, 0, 0);                                                           \
        __builtin_amdgcn_global_load_lds(                                        \
            (const __attribute__((address_space(1))) unsigned*)(_src + 8192 + off0), \
            (__attribute__((address_space(3))) unsigned*)(&tile[slot][8192 + off0]), \
            16, 0, 0);                                                           \
        __builtin_amdgcn_global_load_lds(                                        \
            (const __attribute__((address_space(1))) unsigned*)(_src + 8192 + off1), \
            (__attribute__((address_space(3))) unsigned*)(&tile[slot][8192 + off1]), \
            16, 0, 0);                                                           \
    } while (0)

// one tile's MFMA accumulation from LDS (bfrag in batches of 4)
#define TILE_MFMA(accv, tbase)                                                   \
    do {                                                                         \
        _Pragma("unroll")                                                        \
        for (int g = 0; g < 2; ++g) {                                            \
            short8 bf[4];                                                        \
            _Pragma("unroll")                                                    \
            for (int kk = 0; kk < 4; ++kk)                                       \
                bf[kk] = *(const short8*)((tbase) + (g * 4 + kk) * 1024);        \
            _Pragma("unroll")                                                    \
            for (int kk = 0; kk < 4; ++kk) {                                     \
                _Pragma("unroll")                                                \
                for (int nt = 0; nt < 4; ++nt)                                   \
                    accv[nt] = __builtin_amdgcn_mfma_f32_16x16x32_bf16(          \
                        afrag[nt][g * 4 + kk], bf[kk], accv[nt], 0, 0, 0);       \
            }                                                                    \
        }                                                                        \
    } while (0)

// epilogue: sin -> 3-ch dot -> intra-wave reduce -> red strip at t16
#define EPILOGUE(accv, t16)                                                      \
    do {                                                                         \
        float p0 = 0.f, p1 = 0.f, p2 = 0.f;                                      \
        _Pragma("unroll")                                                        \
        for (int nt = 0; nt < 4; ++nt) {                                         \
            _Pragma("unroll")                                                    \
            for (int r = 0; r < 4; ++r) {                                        \
                const float s = __sinf(accv[nt][r]);                             \
                p0 += qw2r[0][nt][r] * s;                                        \
                p1 += qw2r[1][nt][r] * s;                                        \
                p2 += qw2r[2][nt][r] * s;                                        \
            }                                                                    \
        }                                                                        \
        p0 += __shfl_xor(p0, 16); p0 += __shfl_xor(p0, 32);                      \
        p1 += __shfl_xor(p1, 16); p1 += __shfl_xor(p1, 32);                      \
        p2 += __shfl_xor(p2, 16); p2 += __shfl_xor(p2, 32);                      \
        if (l < 16) {                                                            \
            const int ic = (t16) * 16 + l;                                       \
            red[w][0][ic] = p0;                                                  \
            red[w][1][ic] = p1;                                                  \
            red[w][2][ic] = p2;                                                  \
        }                                                                        \
    } while (0)

    // prologue: stage supersteps 0 (tiles 0,1) and 1 (tiles 2,3)
    STAGE2(0, 0);
    STAGE2(1, 1);
    asm volatile("s_waitcnt vmcnt(4)" ::: "memory");   // slot0 ready
    asm volatile("s_barrier" ::: "memory");

    int cur = 0;
    for (int ss = 0; ss < 32; ++ss) {
        // ---- compute 2 tiles from slot cur with independent chains ----
        f32x4 accA[4], accB[4];
        #pragma unroll
        for (int nt = 0; nt < 4; ++nt) {
            accA[nt][0] = qb1r[nt][0]; accA[nt][1] = qb1r[nt][1];
            accA[nt][2] = qb1r[nt][2]; accA[nt][3] = qb1r[nt][3];
            accB[nt][0] = qb1r[nt][0]; accB[nt][1] = qb1r[nt][1];
            accB[nt][2] = qb1r[nt][2]; accB[nt][3] = qb1r[nt][3];
        }
        const char* tbA = &tile[cur][l * 16];
        const char* tbB = &tile[cur][8192 + l * 16];
        TILE_MFMA(accA, tbA);
        TILE_MFMA(accB, tbB);
        const int t16 = 2 * (ss & 7);
        EPILOGUE(accA, t16);
        EPILOGUE(accB, t16 + 1);

        const int sidx = (ss + 2) & 31;
        if ((ss & 7) == 7) {
            // segment flush: red writes drained, all waves synced, then flush
            asm volatile("s_waitcnt lgkmcnt(0)\n\ts_barrier" ::: "memory");
            const int seg = ss >> 3;
            const int ib = j * HH + seg * 256 + tid;
            #pragma unroll
            for (int q = 0; q < 3; ++q) {
                const float v = red[0][q][tid] + red[1][q][tid]
                              + red[2][q][tid] + red[3][q][tid]
                              + (q == 0 ? qb2v0 : (q == 1 ? qb2v1 : qb2v2));
                out[q * (WW * HH) + ib] = 1.0f / (1.0f + __expf(-v));
            }
            asm volatile("s_barrier" ::: "memory");    // red consumed
            if (cur == 0) STAGE2(0, sidx); else STAGE2(1, sidx);
            // 3 stores + 4 new loads outstanding; oldest 4 (prev slot) drained
            asm volatile("s_waitcnt vmcnt(7)" ::: "memory");
        } else {
            asm volatile("s_barrier" ::: "memory");    // all done reading cur
            if (cur == 0) STAGE2(0, sidx); else STAGE2(1, sidx);
            asm volatile("s_waitcnt vmcnt(4)" ::: "memory");  // other slot ready
        }
        cur ^= 1;
    }
#undef STAGE2
#undef TILE_MFMA
#undef EPILOGUE
}

extern "C" void kernel_launch(void* const* d_in, const int* in_sizes, int n_in,
                              void* d_out, int out_size, void* d_ws, size_t ws_size,
                              hipStream_t stream)
{
    const float* x   = (const float*)d_in[0];
    const float* y   = (const float*)d_in[1];
    const float* bw0 = (const float*)d_in[2];
    const float* bb0 = (const float*)d_in[3];
    const float* bw1 = (const float*)d_in[4];
    const float* bb1 = (const float*)d_in[5];
    const float* pw1 = (const float*)d_in[6];
    const float* pb1 = (const float*)d_in[7];
    const float* pw2 = (const float*)d_in[8];
    const float* pb2 = (const float*)d_in[9];
    const float* qw1 = (const float*)d_in[10];
    const float* qb1 = (const float*)d_in[11];
    const float* qw2 = (const float*)d_in[12];
    const float* qb2 = (const float*)d_in[13];

    char* ws = (char*)d_ws;
    unsigned short* fxT = (unsigned short*)(ws);                  // 512 KB (frag order)
    float* fy_f = (float*)(ws + (512 << 10));                     // 1 MB
    float* pw1t = (float*)(ws + (1536 << 10));                    // 256 KB
    float* pw2t = (float*)(ws + (1792 << 10));                    // 256 KB
    float* s0   = (float*)(ws + (2048 << 10));                    // 2 MB
    float* s1   = (float*)(ws + (4096 << 10));                    // 2 MB
    float* out  = (float*)d_out;

    transpose_k<<<dim3(8, 8, 2), 256, 0, stream>>>(pw1, pw2, pw1t, pw2t);
    branch_k<<<256, 256, 0, stream>>>(x, y, bw0, bb0, bw1, bb1, s0);
    layer_k<<<256, 256, 0, stream>>>(s0, pw1t, pb1, s1, nullptr, nullptr, 0);
    layer_k<<<256, 256, 0, stream>>>(s1, pw2t, pb2, nullptr, fxT, fy_f, 1);
    fused_k<<<WW, 256, 0, stream>>>(qw1, qb1, qw2, qb2, fxT, fy_f, out);
}